// Round 2
// baseline (174.024 us; speedup 1.0000x reference)
//
#include <hip/hip_runtime.h>

#define NT 64
#define NB 8192
#define NS 32
#define NF 16
#define DT 0.05f
#define FP_ITERS 3
#define YROW 72   // floats per batch row in Y LDS: [0,32) real y, [36,68) dummy
                  // sink for h=1 writes (branch-free predication). 72 mod 32 = 8
                  // rotates row bank offsets; reads of the 4 (b,h) groups land on
                  // disjoint bank quads -> conflict-free b128 reads.

typedef float f32x2 __attribute__((ext_vector_type(2)));
typedef float f32x4 __attribute__((ext_vector_type(4)));

// tanh(x) = 1 - 2/(1 + exp2(K x)), K = 2*log2(e). 6 VALU ops per pair.
__device__ __forceinline__ f32x2 tanh2(f32x2 x) {
    const float K = 2.8853900817779268f;
    float e0 = __builtin_amdgcn_exp2f(K * x[0]);
    float e1 = __builtin_amdgcn_exp2f(K * x[1]);
    float r0 = __builtin_amdgcn_rcpf(e0 + 1.0f);
    float r1 = __builtin_amdgcn_rcpf(e1 + 1.0f);
    f32x2 r;
    r[0] = fmaf(-2.0f, r0, 1.0f);
    r[1] = fmaf(-2.0f, r1, 1.0f);
    return r;
}

// xor-16 lane exchange via ds_swizzle (imm 0x401F = BitMode xor 16, and 0x1F).
// Operates within 32-lane groups -> stays inside each batch's lane group.
__device__ __forceinline__ f32x2 swz16(f32x2 v) {
    f32x2 r;
    r[0] = __int_as_float(__builtin_amdgcn_ds_swizzle(__float_as_int(v[0]), 0x401F));
    r[1] = __int_as_float(__builtin_amdgcn_ds_swizzle(__float_as_int(v[1]), 0x401F));
    return r;
}

// Lane map: lane = b*32 + h*16 + p. b in [0,2) = batch within wave, h in [0,2)
// = k-half (this lane accumulates W-dot over k in [h*16, h*16+16)), p in [0,16)
// = state pair (states 2p, 2p+1). 2 batches/wave -> 4096 waves = 4/SIMD:
// doubles TLP vs the 4-batch layout (R1 counters: VALUBusy 51%, occupancy
// grid-capped at 2/SIMD -> latency-bound). Halves of the dot are combined with
// one intra-wave ds_swizzle xor-16 per iteration. y-exchange stays intra-wave:
// lockstep + in-order DS pipe make it barrier-free (validated R2-R5 prev session).
__global__ __launch_bounds__(256, 4) void rnes_kernel(
    const float* __restrict__ y0,
    const float* __restrict__ forces,
    const float* __restrict__ W,
    const float* __restrict__ U,
    const float* __restrict__ bias,
    float* __restrict__ out)
{
    const int lane = threadIdx.x & 63;
    const int wv   = threadIdx.x >> 6;
    const int b    = lane >> 5;
    const int h    = (lane >> 4) & 1;
    const int p    = lane & 15;
    const int batch = blockIdx.x * 8 + wv * 2 + b;

    __shared__ __align__(16) float Ysh[4][2 * YROW];
    float* Yw = Ysh[wv] + b * YROW;          // this batch's row
    float* Ywr = Yw + h * 36;                // write target: real row (h=0) or dummy (h=1)

    // W2[kl] = (W[2p][h*16+kl], W[2p+1][h*16+kl]) — 32 VGPRs (half of k per lane)
    f32x2 W2[16];
#pragma unroll
    for (int c = 0; c < 16; c += 4) {
        f32x4 r0 = *(const f32x4*)(W + (2*p)   * NS + h*16 + c);
        f32x4 r1 = *(const f32x4*)(W + (2*p+1) * NS + h*16 + c);
#pragma unroll
        for (int e = 0; e < 4; ++e) W2[c+e] = (f32x2){r0[e], r1[e]};
    }
    // U2[fl] = (U[2p][h*8+fl], U[2p+1][h*8+fl]) — 16 VGPRs (half of f per lane)
    f32x2 U2[8];
#pragma unroll
    for (int c = 0; c < 8; c += 4) {
        f32x4 r0 = *(const f32x4*)(U + (2*p)   * NF + h*8 + c);
        f32x4 r1 = *(const f32x4*)(U + (2*p+1) * NF + h*8 + c);
#pragma unroll
        for (int e = 0; e < 4; ++e) U2[c+e] = (f32x2){r0[e], r1[e]};
    }
    // bias folded into h=0's fu partial only (summed once after the xor-add)
    f32x2 bh = (f32x2){0.f, 0.f};
    if (h == 0) bh = *(const f32x2*)(bias + 2*p);

    // y_prev, out[0] = y0, seed Y LDS with warm start (h=1 -> dummy row)
    f32x2 yp = *(const f32x2*)(y0 + (size_t)batch * NS + 2*p);
    if (h == 0)
        __builtin_nontemporal_store(yp, (f32x2*)(out + (size_t)batch * NS + 2*p));
    *(f32x2*)(Ywr + 2*p) = yp;
    asm volatile("" ::: "memory");

    // register prefetch of forces[1]: this lane needs only its f-half (8 floats).
    // nontemporal: each force line is read exactly once (broadcast in groups).
    const size_t f4step = (size_t)NB * NF / 4;   // f32x4 units per time step
    const f32x4* fb = (const f32x4*)(forces + (size_t)batch * NF) + h * 2;
    f32x4 u0 = __builtin_nontemporal_load(fb + f4step);
    f32x4 u1 = __builtin_nontemporal_load(fb + f4step + 1);

    for (int k = 1; k < NT; ++k) {
        // fu partial = (bias if h==0) + sum over this lane's f-half
        f32x2 a0 = bh, a1 = (f32x2){0.f, 0.f};
        a0 = U2[0] * u0[0] + a0;
        a1 = U2[1] * u0[1] + a1;
        a0 = U2[2] * u0[2] + a0;
        a1 = U2[3] * u0[3] + a1;
        a0 = U2[4] * u1[0] + a0;
        a1 = U2[5] * u1[1] + a1;
        a0 = U2[6] * u1[2] + a0;
        a1 = U2[7] * u1[3] + a1;
        const f32x2 fu = a0 + a1;

        // prefetch next step's forces (in flight across all 3 iterations)
        {
            int kn = (k + 1 < NT) ? (k + 1) : (NT - 1);
            u0 = __builtin_nontemporal_load(fb + (size_t)kn * f4step);
            u1 = __builtin_nontemporal_load(fb + (size_t)kn * f4step + 1);
        }

        // fixed-point iterations, warm start y_prev (already in LDS)
        f32x2 y = yp;
#pragma unroll
        for (int it = 0; it < FP_ITERS; ++it) {
            f32x2 z0 = fu, z1 = (f32x2){0.f, 0.f};
            const f32x4* Yr = (const f32x4*)(Yw + h * 16);
#pragma unroll
            for (int i = 0; i < 4; ++i) {
                f32x4 yv = Yr[i];                 // broadcast within (b,h) group
                z0 = W2[4*i+0] * yv[0] + z0;
                z1 = W2[4*i+1] * yv[1] + z1;
                z0 = W2[4*i+2] * yv[2] + z0;
                z1 = W2[4*i+3] * yv[3] + z1;
            }
            f32x2 z = z0 + z1;                    // this half's partial (incl. fu)
            f32x2 zt = z + swz16(z);              // + other half: full W y + fu
            f32x2 t = tanh2(zt);
            y[0] = fmaf(DT, t[0], yp[0]);
            y[1] = fmaf(DT, t[1], yp[1]);
            // wave-lockstep: all reads above issued before this write; DS pipe
            // is in-order per wave; clobbers pin compiler ordering.
            asm volatile("" ::: "memory");
            *(f32x2*)(Ywr + 2*p) = y;   // h=0 -> real row (seeds next read); h=1 -> dummy
            asm volatile("" ::: "memory");
        }

        yp = y;
        if (h == 0)
            __builtin_nontemporal_store(y, (f32x2*)(out + ((size_t)k * NB + batch) * NS + 2*p));
    }
}

extern "C" void kernel_launch(void* const* d_in, const int* in_sizes, int n_in,
                              void* d_out, int out_size, void* d_ws, size_t ws_size,
                              hipStream_t stream) {
    const float* y0     = (const float*)d_in[0];
    const float* forces = (const float*)d_in[1];
    const float* W      = (const float*)d_in[2];
    const float* U      = (const float*)d_in[3];
    const float* b      = (const float*)d_in[4];
    float* out = (float*)d_out;

    dim3 grid(NB / 8);    // 1024 blocks x 4 waves x 2 batches = 8192
    dim3 block(256);
    rnes_kernel<<<grid, block, 0, stream>>>(y0, forces, W, U, b, out);
}